// Round 1
// baseline (520.117 us; speedup 1.0000x reference)
//
#include <hip/hip_runtime.h>
#include <hip/hip_bf16.h>

// Fused causal attention head. B=4096, T=33, C=512, DK=64.
// q=x@Wq^T, k=x@Wk^T, v=x@Wv^T, S = q k^T * C^-0.5, causal softmax, out = P v.
// fp32 in/out; bf16 internal.
//
// R5 (theory: latency/occupancy-bound; all pipes sum to ~110us of 452us):
//  (1) chunked double-buffered x staging (4 x 128-col chunks, buf[5] regs)
//      -> next chunk's HBM loads overlap current chunk's QKV MFMAs.
//  (2) row-split tail: wave w owns S rows [16w,16w+16) -> 6 S-MFMAs + 8
//      PV-MFMAs per wave (was 18+6 with 4x redundant full-S), P strips
//      19.0KB -> 6.9KB, softmax VALU /3. Wave 3 exits after scatter.
//  (3) LDS 37728 -> 25632 B, __launch_bounds__(256,5): 4 -> 5 blocks/CU.

typedef __attribute__((ext_vector_type(8))) short bf16x8;
typedef __attribute__((ext_vector_type(4))) float floatx4;

#define NB 4096
#define TT 33
#define CC 512

#define CHS 136       // chunk row stride (ushort): 128 data + 8 pad (68 dw == 4 mod 32)
#define QS  72        // q/k/vT/P stride (ushort): 36 dw == 4 mod 32
// chunk buffers (dead after QKV):
#define OFF_C0 0
#define OFF_C1 8976   // 33*136*2
// overlay (aliases chunk buffers; valid after QKV barrier):
#define OFF_Q  0
#define OFF_K  4752   // 33*72*2
#define OFF_VT 9504   // + 64*72*2 = 9216
#define OFF_P  18720  // 3 strips x 16*72*2 = 6912
#define SMEM_BYTES 25632

__device__ __forceinline__ ushort f2b(float f) {
    union { __hip_bfloat16 h; ushort u; } cv;
    cv.h = __float2bfloat16(f);   // RNE
    return cv.u;
}
__device__ __forceinline__ int imin(int a, int b) { return a < b ? a : b; }

__device__ __forceinline__ bf16x8 load8_b(const ushort* p) { return *(const bf16x8*)p; }
__device__ __forceinline__ bf16x8 load8_f(const float* p) {
    float4 f0 = *(const float4*)p;
    float4 f1 = *(const float4*)(p + 4);
    bf16x8 r;
    r[0] = (short)f2b(f0.x); r[1] = (short)f2b(f0.y);
    r[2] = (short)f2b(f0.z); r[3] = (short)f2b(f0.w);
    r[4] = (short)f2b(f1.x); r[5] = (short)f2b(f1.y);
    r[6] = (short)f2b(f1.z); r[7] = (short)f2b(f1.w);
    return r;
}

// Prep: W (3 x [64,512] fp32) -> bf16 in ws. grid (32,3) x 256.
__global__ void conv_w_kernel(const float* __restrict__ Wq,
                              const float* __restrict__ Wk,
                              const float* __restrict__ Wv,
                              ushort* __restrict__ wb) {
    const float* src = (blockIdx.y == 0) ? Wq : (blockIdx.y == 1) ? Wk : Wv;
    int i = (blockIdx.x * 256 + threadIdx.x) * 4;
    float4 f = *(const float4*)&src[i];
    ushort4 u;
    u.x = f2b(f.x); u.y = f2b(f.y); u.z = f2b(f.z); u.w = f2b(f.w);
    *(ushort4*)&wb[(size_t)blockIdx.y * 32768 + i] = u;
}

template <bool USE_WS>
__global__ __launch_bounds__(256, 5) void head_kernel(
    const float* __restrict__ x,
    const ushort* __restrict__ wb,
    const float* __restrict__ Wqf,
    const float* __restrict__ Wkf,
    const float* __restrict__ Wvf,
    float* __restrict__ out)
{
    __shared__ __align__(16) char smem[SMEM_BYTES];
    ushort* xc0  = (ushort*)(smem + OFF_C0);
    ushort* xc1  = (ushort*)(smem + OFF_C1);
    ushort* q_s  = (ushort*)(smem + OFF_Q);
    ushort* k_s  = (ushort*)(smem + OFF_K);
    ushort* vT_s = (ushort*)(smem + OFF_VT);

    const int b    = blockIdx.x;
    const int tid  = threadIdx.x;
    const int lane = tid & 63;
    const int wave = tid >> 6;
    const int l15  = lane & 15;
    const int quad = lane >> 4;

    const float* xg = x + (size_t)b * (TT * CC);

    // ---- W fragment pointers (per thread) ----
    int nidx[3];
    const ushort* wrow_b[3];
    const float*  wrow_f[3];
    #pragma unroll
    for (int nl = 0; nl < 3; nl++) {
        int n = wave * 3 + nl;
        nidx[nl] = n;
        int mat = n >> 2;
        int row = (n & 3) * 16 + l15;
        if (USE_WS) {
            wrow_b[nl] = wb + (size_t)mat * 32768 + (size_t)row * CC;
            wrow_f[nl] = nullptr;
        } else {
            const float* Wf = (mat == 0) ? Wqf : (mat == 1) ? Wkf : Wvf;
            wrow_f[nl] = Wf + (size_t)row * CC;
            wrow_b[nl] = nullptr;
        }
    }

    // ---- chunked staging helpers ----
    // chunk c covers x cols [c*128, c*128+128): 33*32 = 1056 float4 loads.
    float4 buf[5];
    auto LOADCHUNK = [&](int c) {
        #pragma unroll
        for (int j = 0; j < 5; j++) {
            int i = tid + j * 256;
            if (i < 1056) {
                int r = i >> 5, c4 = i & 31;
                buf[j] = ((const float4*)xg)[r * 128 + c * 32 + c4];
            }
        }
    };
    auto WRITECHUNK = [&](ushort* dst) {
        #pragma unroll
        for (int j = 0; j < 5; j++) {
            int i = tid + j * 256;
            if (i < 1056) {
                int r = i >> 5, c4 = i & 31;
                ushort4 u;
                u.x = f2b(buf[j].x); u.y = f2b(buf[j].y);
                u.z = f2b(buf[j].z); u.w = f2b(buf[j].w);
                *(ushort4*)&dst[r * CHS + c4 * 4] = u;
            }
        }
    };

    // ---- Phase 0/1 interleaved: stage chunk, QKV MFMA, prefetch next ----
    LOADCHUNK(0);
    WRITECHUNK(xc0);
    __syncthreads();

    floatx4 acc[3][3] = {};   // [m][nl], accumulated over all 4 chunks
    const int r0 = l15, r1 = 16 + l15, r2 = 32;   // m=2 tile clamped to 32

    #pragma unroll
    for (int c = 0; c < 4; c++) {
        if (c < 3) LOADCHUNK(c + 1);          // HBM latency hides under MFMAs
        const ushort* xs = (c & 1) ? xc1 : xc0;
        #pragma unroll
        for (int ksl = 0; ksl < 4; ksl++) {
            int col  = ksl * 32 + quad * 8;   // within chunk
            int wcol = c * 128 + col;         // global k index
            bf16x8 a0 = *(const bf16x8*)&xs[r0 * CHS + col];
            bf16x8 a1 = *(const bf16x8*)&xs[r1 * CHS + col];
            bf16x8 a2 = *(const bf16x8*)&xs[r2 * CHS + col];
            bf16x8 b0 = USE_WS ? load8_b(&wrow_b[0][wcol]) : load8_f(&wrow_f[0][wcol]);
            bf16x8 b1 = USE_WS ? load8_b(&wrow_b[1][wcol]) : load8_f(&wrow_f[1][wcol]);
            bf16x8 b2 = USE_WS ? load8_b(&wrow_b[2][wcol]) : load8_f(&wrow_f[2][wcol]);
            acc[0][0] = __builtin_amdgcn_mfma_f32_16x16x32_bf16(a0, b0, acc[0][0], 0, 0, 0);
            acc[1][0] = __builtin_amdgcn_mfma_f32_16x16x32_bf16(a1, b0, acc[1][0], 0, 0, 0);
            acc[2][0] = __builtin_amdgcn_mfma_f32_16x16x32_bf16(a2, b0, acc[2][0], 0, 0, 0);
            acc[0][1] = __builtin_amdgcn_mfma_f32_16x16x32_bf16(a0, b1, acc[0][1], 0, 0, 0);
            acc[1][1] = __builtin_amdgcn_mfma_f32_16x16x32_bf16(a1, b1, acc[1][1], 0, 0, 0);
            acc[2][1] = __builtin_amdgcn_mfma_f32_16x16x32_bf16(a2, b1, acc[2][1], 0, 0, 0);
            acc[0][2] = __builtin_amdgcn_mfma_f32_16x16x32_bf16(a0, b2, acc[0][2], 0, 0, 0);
            acc[1][2] = __builtin_amdgcn_mfma_f32_16x16x32_bf16(a1, b2, acc[1][2], 0, 0, 0);
            acc[2][2] = __builtin_amdgcn_mfma_f32_16x16x32_bf16(a2, b2, acc[2][2], 0, 0, 0);
        }
        if (c < 3) WRITECHUNK((c & 1) ? xc0 : xc1);
        __syncthreads();   // chunk c+1 visible; after c=3: chunk bufs dead, overlay ok
    }

    // ---- Phase 2: zero vT strip t in [33,64), scatter q/k/vT ----
    for (int i = tid; i < 64 * 32; i += 256) {
        int d = i >> 5, t = i & 31;
        if (t) vT_s[d * QS + 32 + t] = 0;   // t = 33..63 (avoid NaN * 0 in PV)
    }
    #pragma unroll
    for (int nl = 0; nl < 3; nl++) {
        int n = nidx[nl];
        int mat = n >> 2;                  // 0=q 1=k 2=v
        int col = (n & 3) * 16 + l15;
        #pragma unroll
        for (int m = 0; m < 3; m++) {
            #pragma unroll
            for (int r = 0; r < 4; r++) {
                int row = m * 16 + quad * 4 + r;   // t (C/D layout, m89)
                if (row < TT) {
                    ushort v = f2b(acc[m][nl][r]);
                    if (mat == 0)      q_s[row * QS + col] = v;
                    else if (mat == 1) k_s[row * QS + col] = v;
                    else               vT_s[col * QS + row] = v;
                }
            }
        }
    }
    __syncthreads();   // barrier: q/k/vT complete. Tail is barrier-free.

    // ---- Tail (row-split): wave w owns S/out rows [16w, 16w+16), w<3 ----
    if (wave >= 3) return;
    const int rowbase = wave * 16;
    ushort* Pw = (ushort*)(smem + OFF_P) + wave * (16 * QS);  // wave-private strip

    // S strip = q[rows] @ k^T (all 48 padded cols)
    int qr = imin(rowbase + l15, 32);
    bf16x8 aq0 = *(const bf16x8*)&q_s[qr * QS + quad * 8];
    bf16x8 aq1 = *(const bf16x8*)&q_s[qr * QS + 32 + quad * 8];
    floatx4 s[3] = {};
    #pragma unroll
    for (int nt = 0; nt < 3; nt++) {
        int kr = imin(nt * 16 + l15, 32);
        bf16x8 bk0 = *(const bf16x8*)&k_s[kr * QS + quad * 8];
        bf16x8 bk1 = *(const bf16x8*)&k_s[kr * QS + 32 + quad * 8];
        s[nt] = __builtin_amdgcn_mfma_f32_16x16x32_bf16(aq0, bk0, s[nt], 0, 0, 0);
        s[nt] = __builtin_amdgcn_mfma_f32_16x16x32_bf16(aq1, bk1, s[nt], 0, 0, 0);
    }

    const float scale = 0.044194173824159216f;  // 512^-0.5
    #pragma unroll
    for (int nt = 0; nt < 3; nt++)
        #pragma unroll
        for (int r = 0; r < 4; r++) {
            int row = rowbase + quad * 4 + r;
            int col = nt * 16 + l15;
            float v = s[nt][r] * scale;
            s[nt][r] = (col <= row) ? v : -1e30f;
        }
    // row-wise max & sum via 16-lane butterflies (cols live on l15)
    float inv_s[4];
    #pragma unroll
    for (int r = 0; r < 4; r++) {
        float m = fmaxf(fmaxf(s[0][r], s[1][r]), s[2][r]);
        #pragma unroll
        for (int d = 1; d < 16; d <<= 1) m = fmaxf(m, __shfl_xor(m, d));
        float sum = 0.f;
        #pragma unroll
        for (int nt = 0; nt < 3; nt++) {
            float e = __expf(s[nt][r] - m);
            s[nt][r] = e;
            sum += e;
        }
        #pragma unroll
        for (int d = 1; d < 16; d <<= 1) sum += __shfl_xor(sum, d);
        inv_s[r] = 1.f / sum;
    }

    // P strip -> private LDS (16 rows x 64 cols; 33..47 are exp->0, zero 48..63)
    for (int i = lane; i < 16 * 8; i += 64) {
        int r = i >> 3, c = 48 + ((i & 7) << 1);
        *(uint*)&Pw[r * QS + c] = 0u;
    }
    #pragma unroll
    for (int nt = 0; nt < 3; nt++)
        #pragma unroll
        for (int r = 0; r < 4; r++)
            Pw[(quad * 4 + r) * QS + nt * 16 + l15] = f2b(s[nt][r]);

    // PV: out[rows, 0:64] = P_strip @ v ; 1/sum in fp32 epilogue
    bf16x8 ap0 = *(const bf16x8*)&Pw[l15 * QS + quad * 8];
    bf16x8 ap1 = *(const bf16x8*)&Pw[l15 * QS + 32 + quad * 8];
    float* og = out + (size_t)b * (TT * 64);
    #pragma unroll
    for (int nt2 = 0; nt2 < 4; nt2++) {
        int dcol = nt2 * 16 + l15;
        bf16x8 bv0 = *(const bf16x8*)&vT_s[dcol * QS + quad * 8];
        bf16x8 bv1 = *(const bf16x8*)&vT_s[dcol * QS + 32 + quad * 8];
        floatx4 o = {};
        o = __builtin_amdgcn_mfma_f32_16x16x32_bf16(ap0, bv0, o, 0, 0, 0);
        o = __builtin_amdgcn_mfma_f32_16x16x32_bf16(ap1, bv1, o, 0, 0, 0);
        #pragma unroll
        for (int r = 0; r < 4; r++) {
            int row = rowbase + quad * 4 + r;
            if (row < TT) og[row * 64 + dcol] = o[r] * inv_s[r];
        }
    }
}

extern "C" void kernel_launch(void* const* d_in, const int* in_sizes, int n_in,
                              void* d_out, int out_size, void* d_ws, size_t ws_size,
                              hipStream_t stream) {
    const float* x  = (const float*)d_in[0];
    const float* Wq = (const float*)d_in[1];
    const float* Wk = (const float*)d_in[2];
    const float* Wv = (const float*)d_in[3];
    float* out = (float*)d_out;

    if (ws_size >= 3u * 64u * 512u * sizeof(ushort)) {
        ushort* wb = (ushort*)d_ws;
        conv_w_kernel<<<dim3(32, 3), 256, 0, stream>>>(Wq, Wk, Wv, wb);
        head_kernel<true><<<NB, 256, 0, stream>>>(x, wb, nullptr, nullptr, nullptr, out);
    } else {
        head_kernel<false><<<NB, 256, 0, stream>>>(x, nullptr, Wq, Wk, Wv, out);
    }
}

// Round 2
// 430.682 us; speedup vs baseline: 1.2077x; 1.2077x over previous
//
#include <hip/hip_runtime.h>
#include <hip/hip_bf16.h>

// Fused causal attention head. B=4096, T=33, C=512, DK=64.
// q=x@Wq^T, k=x@Wk^T, v=x@Wv^T, S = q k^T * C^-0.5, causal softmax, out = P v.
// fp32 in/out; bf16 internal.
//
// R6: single change vs R5 -- __launch_bounds__(256,4).
// R5's (256,5) capped the unified VGPR+AGPR budget at 96 (counter showed
// 48 arch + 48 acc = 96 exactly); demand is ~120-140, so loop-carried state
// spilled to scratch: WRITE_SIZE 232MB vs 34.6MB of actual output (~48KB/block
// of spill traffic), every pipe <10% busy, dispatch 252us. Budget 128 fits
// demand -> no spill. Occupancy measured 48.5% anyway, so the 5th block was
// free to give up.
//
// Carried from R5:
//  (1) chunked double-buffered x staging (4 x 128-col chunks, buf[5] regs)
//  (2) row-split tail: wave w owns S rows [16w,16w+16); wave 3 exits
//  (3) LDS 25632 B

typedef __attribute__((ext_vector_type(8))) short bf16x8;
typedef __attribute__((ext_vector_type(4))) float floatx4;

#define NB 4096
#define TT 33
#define CC 512

#define CHS 136       // chunk row stride (ushort): 128 data + 8 pad (68 dw == 4 mod 32)
#define QS  72        // q/k/vT/P stride (ushort): 36 dw == 4 mod 32
// chunk buffers (dead after QKV):
#define OFF_C0 0
#define OFF_C1 8976   // 33*136*2
// overlay (aliases chunk buffers; valid after QKV barrier):
#define OFF_Q  0
#define OFF_K  4752   // 33*72*2
#define OFF_VT 9504   // + 64*72*2 = 9216
#define OFF_P  18720  // 3 strips x 16*72*2 = 6912
#define SMEM_BYTES 25632

__device__ __forceinline__ ushort f2b(float f) {
    union { __hip_bfloat16 h; ushort u; } cv;
    cv.h = __float2bfloat16(f);   // RNE
    return cv.u;
}
__device__ __forceinline__ int imin(int a, int b) { return a < b ? a : b; }

__device__ __forceinline__ bf16x8 load8_b(const ushort* p) { return *(const bf16x8*)p; }
__device__ __forceinline__ bf16x8 load8_f(const float* p) {
    float4 f0 = *(const float4*)p;
    float4 f1 = *(const float4*)(p + 4);
    bf16x8 r;
    r[0] = (short)f2b(f0.x); r[1] = (short)f2b(f0.y);
    r[2] = (short)f2b(f0.z); r[3] = (short)f2b(f0.w);
    r[4] = (short)f2b(f1.x); r[5] = (short)f2b(f1.y);
    r[6] = (short)f2b(f1.z); r[7] = (short)f2b(f1.w);
    return r;
}

// Prep: W (3 x [64,512] fp32) -> bf16 in ws. grid (32,3) x 256.
__global__ void conv_w_kernel(const float* __restrict__ Wq,
                              const float* __restrict__ Wk,
                              const float* __restrict__ Wv,
                              ushort* __restrict__ wb) {
    const float* src = (blockIdx.y == 0) ? Wq : (blockIdx.y == 1) ? Wk : Wv;
    int i = (blockIdx.x * 256 + threadIdx.x) * 4;
    float4 f = *(const float4*)&src[i];
    ushort4 u;
    u.x = f2b(f.x); u.y = f2b(f.y); u.z = f2b(f.z); u.w = f2b(f.w);
    *(ushort4*)&wb[(size_t)blockIdx.y * 32768 + i] = u;
}

template <bool USE_WS>
__global__ __launch_bounds__(256, 4) void head_kernel(
    const float* __restrict__ x,
    const ushort* __restrict__ wb,
    const float* __restrict__ Wqf,
    const float* __restrict__ Wkf,
    const float* __restrict__ Wvf,
    float* __restrict__ out)
{
    __shared__ __align__(16) char smem[SMEM_BYTES];
    ushort* xc0  = (ushort*)(smem + OFF_C0);
    ushort* xc1  = (ushort*)(smem + OFF_C1);
    ushort* q_s  = (ushort*)(smem + OFF_Q);
    ushort* k_s  = (ushort*)(smem + OFF_K);
    ushort* vT_s = (ushort*)(smem + OFF_VT);

    const int b    = blockIdx.x;
    const int tid  = threadIdx.x;
    const int lane = tid & 63;
    const int wave = tid >> 6;
    const int l15  = lane & 15;
    const int quad = lane >> 4;

    const float* xg = x + (size_t)b * (TT * CC);

    // ---- W fragment pointers (per thread) ----
    int nidx[3];
    const ushort* wrow_b[3];
    const float*  wrow_f[3];
    #pragma unroll
    for (int nl = 0; nl < 3; nl++) {
        int n = wave * 3 + nl;
        nidx[nl] = n;
        int mat = n >> 2;
        int row = (n & 3) * 16 + l15;
        if (USE_WS) {
            wrow_b[nl] = wb + (size_t)mat * 32768 + (size_t)row * CC;
            wrow_f[nl] = nullptr;
        } else {
            const float* Wf = (mat == 0) ? Wqf : (mat == 1) ? Wkf : Wvf;
            wrow_f[nl] = Wf + (size_t)row * CC;
            wrow_b[nl] = nullptr;
        }
    }

    // ---- chunked staging helpers ----
    // chunk c covers x cols [c*128, c*128+128): 33*32 = 1056 float4 loads.
    float4 buf[5];
    auto LOADCHUNK = [&](int c) {
        #pragma unroll
        for (int j = 0; j < 5; j++) {
            int i = tid + j * 256;
            if (i < 1056) {
                int r = i >> 5, c4 = i & 31;
                buf[j] = ((const float4*)xg)[r * 128 + c * 32 + c4];
            }
        }
    };
    auto WRITECHUNK = [&](ushort* dst) {
        #pragma unroll
        for (int j = 0; j < 5; j++) {
            int i = tid + j * 256;
            if (i < 1056) {
                int r = i >> 5, c4 = i & 31;
                ushort4 u;
                u.x = f2b(buf[j].x); u.y = f2b(buf[j].y);
                u.z = f2b(buf[j].z); u.w = f2b(buf[j].w);
                *(ushort4*)&dst[r * CHS + c4 * 4] = u;
            }
        }
    };

    // ---- Phase 0/1 interleaved: stage chunk, QKV MFMA, prefetch next ----
    LOADCHUNK(0);
    WRITECHUNK(xc0);
    __syncthreads();

    floatx4 acc[3][3] = {};   // [m][nl], accumulated over all 4 chunks
    const int r0 = l15, r1 = 16 + l15, r2 = 32;   // m=2 tile clamped to 32

    #pragma unroll
    for (int c = 0; c < 4; c++) {
        if (c < 3) LOADCHUNK(c + 1);          // HBM latency hides under MFMAs
        const ushort* xs = (c & 1) ? xc1 : xc0;
        #pragma unroll
        for (int ksl = 0; ksl < 4; ksl++) {
            int col  = ksl * 32 + quad * 8;   // within chunk
            int wcol = c * 128 + col;         // global k index
            bf16x8 a0 = *(const bf16x8*)&xs[r0 * CHS + col];
            bf16x8 a1 = *(const bf16x8*)&xs[r1 * CHS + col];
            bf16x8 a2 = *(const bf16x8*)&xs[r2 * CHS + col];
            bf16x8 b0 = USE_WS ? load8_b(&wrow_b[0][wcol]) : load8_f(&wrow_f[0][wcol]);
            bf16x8 b1 = USE_WS ? load8_b(&wrow_b[1][wcol]) : load8_f(&wrow_f[1][wcol]);
            bf16x8 b2 = USE_WS ? load8_b(&wrow_b[2][wcol]) : load8_f(&wrow_f[2][wcol]);
            acc[0][0] = __builtin_amdgcn_mfma_f32_16x16x32_bf16(a0, b0, acc[0][0], 0, 0, 0);
            acc[1][0] = __builtin_amdgcn_mfma_f32_16x16x32_bf16(a1, b0, acc[1][0], 0, 0, 0);
            acc[2][0] = __builtin_amdgcn_mfma_f32_16x16x32_bf16(a2, b0, acc[2][0], 0, 0, 0);
            acc[0][1] = __builtin_amdgcn_mfma_f32_16x16x32_bf16(a0, b1, acc[0][1], 0, 0, 0);
            acc[1][1] = __builtin_amdgcn_mfma_f32_16x16x32_bf16(a1, b1, acc[1][1], 0, 0, 0);
            acc[2][1] = __builtin_amdgcn_mfma_f32_16x16x32_bf16(a2, b1, acc[2][1], 0, 0, 0);
            acc[0][2] = __builtin_amdgcn_mfma_f32_16x16x32_bf16(a0, b2, acc[0][2], 0, 0, 0);
            acc[1][2] = __builtin_amdgcn_mfma_f32_16x16x32_bf16(a1, b2, acc[1][2], 0, 0, 0);
            acc[2][2] = __builtin_amdgcn_mfma_f32_16x16x32_bf16(a2, b2, acc[2][2], 0, 0, 0);
        }
        if (c < 3) WRITECHUNK((c & 1) ? xc0 : xc1);
        __syncthreads();   // chunk c+1 visible; after c=3: chunk bufs dead, overlay ok
    }

    // ---- Phase 2: zero vT strip t in [33,64), scatter q/k/vT ----
    for (int i = tid; i < 64 * 32; i += 256) {
        int d = i >> 5, t = i & 31;
        if (t) vT_s[d * QS + 32 + t] = 0;   // t = 33..63 (avoid NaN * 0 in PV)
    }
    #pragma unroll
    for (int nl = 0; nl < 3; nl++) {
        int n = nidx[nl];
        int mat = n >> 2;                  // 0=q 1=k 2=v
        int col = (n & 3) * 16 + l15;
        #pragma unroll
        for (int m = 0; m < 3; m++) {
            #pragma unroll
            for (int r = 0; r < 4; r++) {
                int row = m * 16 + quad * 4 + r;   // t (C/D layout, m89)
                if (row < TT) {
                    ushort v = f2b(acc[m][nl][r]);
                    if (mat == 0)      q_s[row * QS + col] = v;
                    else if (mat == 1) k_s[row * QS + col] = v;
                    else               vT_s[col * QS + row] = v;
                }
            }
        }
    }
    __syncthreads();   // barrier: q/k/vT complete. Tail is barrier-free.

    // ---- Tail (row-split): wave w owns S/out rows [16w, 16w+16), w<3 ----
    if (wave >= 3) return;
    const int rowbase = wave * 16;
    ushort* Pw = (ushort*)(smem + OFF_P) + wave * (16 * QS);  // wave-private strip

    // S strip = q[rows] @ k^T (all 48 padded cols)
    int qr = imin(rowbase + l15, 32);
    bf16x8 aq0 = *(const bf16x8*)&q_s[qr * QS + quad * 8];
    bf16x8 aq1 = *(const bf16x8*)&q_s[qr * QS + 32 + quad * 8];
    floatx4 s[3] = {};
    #pragma unroll
    for (int nt = 0; nt < 3; nt++) {
        int kr = imin(nt * 16 + l15, 32);
        bf16x8 bk0 = *(const bf16x8*)&k_s[kr * QS + quad * 8];
        bf16x8 bk1 = *(const bf16x8*)&k_s[kr * QS + 32 + quad * 8];
        s[nt] = __builtin_amdgcn_mfma_f32_16x16x32_bf16(aq0, bk0, s[nt], 0, 0, 0);
        s[nt] = __builtin_amdgcn_mfma_f32_16x16x32_bf16(aq1, bk1, s[nt], 0, 0, 0);
    }

    const float scale = 0.044194173824159216f;  // 512^-0.5
    #pragma unroll
    for (int nt = 0; nt < 3; nt++)
        #pragma unroll
        for (int r = 0; r < 4; r++) {
            int row = rowbase + quad * 4 + r;
            int col = nt * 16 + l15;
            float v = s[nt][r] * scale;
            s[nt][r] = (col <= row) ? v : -1e30f;
        }
    // row-wise max & sum via 16-lane butterflies (cols live on l15)
    float inv_s[4];
    #pragma unroll
    for (int r = 0; r < 4; r++) {
        float m = fmaxf(fmaxf(s[0][r], s[1][r]), s[2][r]);
        #pragma unroll
        for (int d = 1; d < 16; d <<= 1) m = fmaxf(m, __shfl_xor(m, d));
        float sum = 0.f;
        #pragma unroll
        for (int nt = 0; nt < 3; nt++) {
            float e = __expf(s[nt][r] - m);
            s[nt][r] = e;
            sum += e;
        }
        #pragma unroll
        for (int d = 1; d < 16; d <<= 1) sum += __shfl_xor(sum, d);
        inv_s[r] = 1.f / sum;
    }

    // P strip -> private LDS (16 rows x 64 cols; 33..47 are exp->0, zero 48..63)
    for (int i = lane; i < 16 * 8; i += 64) {
        int r = i >> 3, c = 48 + ((i & 7) << 1);
        *(uint*)&Pw[r * QS + c] = 0u;
    }
    #pragma unroll
    for (int nt = 0; nt < 3; nt++)
        #pragma unroll
        for (int r = 0; r < 4; r++)
            Pw[(quad * 4 + r) * QS + nt * 16 + l15] = f2b(s[nt][r]);

    // PV: out[rows, 0:64] = P_strip @ v ; 1/sum in fp32 epilogue
    bf16x8 ap0 = *(const bf16x8*)&Pw[l15 * QS + quad * 8];
    bf16x8 ap1 = *(const bf16x8*)&Pw[l15 * QS + 32 + quad * 8];
    float* og = out + (size_t)b * (TT * 64);
    #pragma unroll
    for (int nt2 = 0; nt2 < 4; nt2++) {
        int dcol = nt2 * 16 + l15;
        bf16x8 bv0 = *(const bf16x8*)&vT_s[dcol * QS + quad * 8];
        bf16x8 bv1 = *(const bf16x8*)&vT_s[dcol * QS + 32 + quad * 8];
        floatx4 o = {};
        o = __builtin_amdgcn_mfma_f32_16x16x32_bf16(ap0, bv0, o, 0, 0, 0);
        o = __builtin_amdgcn_mfma_f32_16x16x32_bf16(ap1, bv1, o, 0, 0, 0);
        #pragma unroll
        for (int r = 0; r < 4; r++) {
            int row = rowbase + quad * 4 + r;
            if (row < TT) og[row * 64 + dcol] = o[r] * inv_s[r];
        }
    }
}

extern "C" void kernel_launch(void* const* d_in, const int* in_sizes, int n_in,
                              void* d_out, int out_size, void* d_ws, size_t ws_size,
                              hipStream_t stream) {
    const float* x  = (const float*)d_in[0];
    const float* Wq = (const float*)d_in[1];
    const float* Wk = (const float*)d_in[2];
    const float* Wv = (const float*)d_in[3];
    float* out = (float*)d_out;

    if (ws_size >= 3u * 64u * 512u * sizeof(ushort)) {
        ushort* wb = (ushort*)d_ws;
        conv_w_kernel<<<dim3(32, 3), 256, 0, stream>>>(Wq, Wk, Wv, wb);
        head_kernel<true><<<NB, 256, 0, stream>>>(x, wb, nullptr, nullptr, nullptr, out);
    } else {
        head_kernel<false><<<NB, 256, 0, stream>>>(x, nullptr, Wq, Wk, Wv, out);
    }
}